// Round 16
// baseline (768.670 us; speedup 1.0000x reference)
//
#include <hip/hip_runtime.h>
#include <math.h>

#define V96 (96*96*96)
#define NDIVBLK 3350    // ceil(95^3/256) 256-cell div units
#define NDIVPAIR 3350   // div-pair blocks (2 units per 512-thread block)
#define NMEDBLK 1728    // 3*24*24 blocks per field (512 voxels/block)
#define NMEDTOT 12096   // 7 * NMEDBLK
#define NTOT 15446      // NMEDTOT + NDIVPAIR

// ---------- helpers ----------

__device__ __forceinline__ int reflect_idx(int t, int n) {
  if (t < 0) t = -t;
  if (t >= n) t = 2 * n - 2 - t;
  return t;
}

// Exact median of 5 (10 min/max ops).
__device__ __forceinline__ float med5(float a, float b, float c, float d,
                                      float e) {
  float f = fmaxf(fminf(a, b), fminf(c, d));
  float g = fminf(fmaxf(a, b), fmaxf(c, d));
  float lo = fminf(f, g);
  float hi = fmaxf(f, g);
  return fmaxf(lo, fminf(hi, e));
}

// On-the-fly masked target fields: bxm(o), bym(o) without materialization.
__device__ __forceinline__ void bmask(const float* __restrict__ pbx,
                                      const float* __restrict__ pby,
                                      const float* __restrict__ bxt,
                                      const float* __restrict__ byt, int o,
                                      float& bx, float& by) {
  float xt = bxt[o];
  float yt = byt[o];
  float m = (pbx[o] * xt + pby[o] * yt > 0.0f) ? 1.0f : -1.0f;
  bx = xt * m;
  by = yt * m;
}

// ---------- single fused kernel: div + med + finalize ----------
// Bresenham interleave of 3350 div-pair blocks among 12096 med blocks.
// Last block (ticket NTOT-1) reduces all partials and emits the 6 scalars.

__global__ __launch_bounds__(512, 8) void mega_kernel(
    const float* __restrict__ pred_b, const float* __restrict__ targets,
    const float* __restrict__ z, double* __restrict__ P,
    double* __restrict__ M, unsigned int* __restrict__ done,
    float* __restrict__ out) {
  __shared__ float raw[8 * 8 * 36];  // [d][h][w] stride 288/36/1
  __shared__ float m1[8 * 8 * 32];   // [d][h][x] stride 256/32/1
  __shared__ float m2[8 * 4 * 32];   // [d][y][x] stride 128/32/1
  __shared__ double sh1[8];
  __shared__ double sh2[8];
  __shared__ double fres[11];
  __shared__ unsigned int tickS;

  const float* pbx = pred_b;
  const float* pby = pred_b + V96;
  const float* bzp = pred_b + 2 * V96;
  const float* bxt = targets;
  const float* byt = targets + V96;
  const float* bzt = targets + 2 * V96;

  const int g = blockIdx.x;
  const int tid = threadIdx.x;
  const int dv0 = (int)(((long long)g * NDIVPAIR) / NTOT);
  const int dv1 = (int)(((long long)(g + 1) * NDIVPAIR) / NTOT);

  if (dv1 != dv0) {
    // ================= div pair #dv0: units 2*dv0 + half =================
    const int half = tid >> 8;
    const int ltid = tid & 255;
    const int dblk = 2 * dv0 + half;
    const int which = (dblk >= NDIVBLK) ? 1 : 0;
    const int blk = dblk - which * NDIVBLK;
    const int N = 95 * 95 * 95;
    int idx = blk * 256 + ltid;
    double fs = 0.0, fq = 0.0;
    if (idx < N) {
      int w = idx % 95;
      int t = idx / 95;
      int h = t % 95;
      int d = t / 95;
      int o = (d * 96 + h) * 96 + w;
      float bxv000, bxv001, bxv010, bxv011, bxv100, bxv101, bxv110, bxv111;
      float byv000, byv001, byv010, byv011, byv100, byv101, byv110, byv111;
      if (which == 0) {
        bxv000 = pbx[o]; bxv001 = pbx[o + 1]; bxv010 = pbx[o + 96];
        bxv011 = pbx[o + 97]; bxv100 = pbx[o + 9216]; bxv101 = pbx[o + 9217];
        bxv110 = pbx[o + 9312]; bxv111 = pbx[o + 9313];
        byv000 = pby[o]; byv001 = pby[o + 1]; byv010 = pby[o + 96];
        byv011 = pby[o + 97]; byv100 = pby[o + 9216]; byv101 = pby[o + 9217];
        byv110 = pby[o + 9312]; byv111 = pby[o + 9313];
      } else {
        bmask(pbx, pby, bxt, byt, o, bxv000, byv000);
        bmask(pbx, pby, bxt, byt, o + 1, bxv001, byv001);
        bmask(pbx, pby, bxt, byt, o + 96, bxv010, byv010);
        bmask(pbx, pby, bxt, byt, o + 97, bxv011, byv011);
        bmask(pbx, pby, bxt, byt, o + 9216, bxv100, byv100);
        bmask(pbx, pby, bxt, byt, o + 9217, bxv101, byv101);
        bmask(pbx, pby, bxt, byt, o + 9312, bxv110, byv110);
        bmask(pbx, pby, bxt, byt, o + 9313, bxv111, byv111);
      }
      float bzv000 = bzt[o], bzv001 = bzt[o + 1], bzv010 = bzt[o + 96],
            bzv011 = bzt[o + 97], bzv100 = bzt[o + 9216],
            bzv101 = bzt[o + 9217], bzv110 = bzt[o + 9312],
            bzv111 = bzt[o + 9313];
      float zv000 = z[o], zv001 = z[o + 1], zv010 = z[o + 96],
            zv011 = z[o + 97], zv100 = z[o + 9216], zv101 = z[o + 9217],
            zv110 = z[o + 9312], zv111 = z[o + 9313];
      float az1 = fabsf(zv001 - zv000);
      float az2 = fabsf(zv011 - zv010);
      float az3 = fabsf(zv101 - zv100);
      float az4 = fabsf(zv111 - zv110);
      const float c6 = 1.0f / 6.0f;
      const float c3 = 1.0f / 3.0f;
      float flux =
          0.25f * (bxv100 + bxv110 + bxv101 + bxv111) * 0.5f * (az3 + az4) -
          0.25f * (bxv000 + bxv010 + bxv001 + bxv011) * 0.5f * (az1 + az2) +
          0.25f * (byv010 + byv110 + byv011 + byv111) * 0.5f * (az2 + az4) -
          0.25f * (byv000 + byv100 + byv001 + byv101) * 0.5f * (az1 + az3) +
          0.5f * ((bzv001 + bzv101 + bzv111) + (bzv001 + bzv111 + bzv011)) *
              c3 -
          0.5f * ((bzv000 + bzv100 + bzv110) + (bzv000 + bzv110 + bzv010)) *
              c3 +
          (bxv001 + bxv101 + bxv111) * (zv001 - zv101) * c6 +
          (bxv001 + bxv011 + bxv111) * (zv011 - zv111) * c6 +
          (byv001 + byv101 + byv111) * (zv101 - zv111) * c6 +
          (byv001 + byv011 + byv111) * (zv001 - zv011) * c6 -
          ((bxv000 + bxv100 + bxv110) * (zv000 - zv100) * c6 +
           (bxv000 + bxv010 + bxv110) * (zv010 - zv110) * c6 +
           (byv000 + byv100 + byv110) * (zv100 - zv110) * c6 +
           (byv000 + byv010 + byv110) * (zv000 - zv010) * c6);
      float sbx = bxv000 + bxv001 + bxv010 + bxv011 + bxv100 + bxv101 +
                  bxv110 + bxv111;
      float sby = byv000 + byv001 + byv010 + byv011 + byv100 + byv101 +
                  byv110 + byv111;
      float sbz = bzv000 + bzv001 + bzv010 + bzv011 + bzv100 + bzv101 +
                  bzv110 + bzv111;
      float ave = 0.015625f * (sbx * sbx + sby * sby + sbz * sbz) + 1e-8f;
      float res = flux * flux;
      float flx1 = res * res / ave;
      fs = (double)flx1;
      fq = (double)flx1 * (double)flx1;
    }
    {
      int lane = tid & 63;
      int wv = tid >> 6;
#pragma unroll
      for (int off = 32; off > 0; off >>= 1) {
        fs += __shfl_down(fs, off, 64);
        fq += __shfl_down(fq, off, 64);
      }
      if (lane == 0) {
        sh1[wv] = fs;
        sh2[wv] = fq;
      }
      __syncthreads();
      if (ltid == 0) {
        double bs = 0.0, bq = 0.0;
#pragma unroll
        for (int i = 0; i < 4; i++) {
          bs += sh1[half * 4 + i];
          bq += sh2[half * 4 + i];
        }
        P[(which ? 2 : 0) * NDIVBLK + blk] = bs;
        P[(which ? 3 : 1) * NDIVBLK + blk] = bq;
        __threadfence();
      }
    }
  } else {
    // ================= med block #(g - dv0) =================
    const int mb = g - dv0;
    const int bxi = mb % 3;
    const int rest = mb / 3;
    const int byi = rest % 24;
    const int bz = rest / 24;
    const int fid = bz / 24;
    const int zb = bz - fid * 24;
    const int W = (fid == 0 || fid == 1) ? 95 : 96;
    const int H = (fid == 0 || fid == 2) ? 95 : 96;
    const int D = (fid == 1 || fid == 2) ? 95 : 96;

    const int w0 = bxi * 32;
    const int h0 = byi * 4;
    const int d0 = zb * 4;

    for (int il = tid; il < 2304; il += 512) {
      int lw = il % 36;
      int lh = (il / 36) % 8;
      int ld = il / 288;
      int gw = reflect_idx(w0 + lw - 2, W);
      int gh = reflect_idx(h0 + lh - 2, H);
      int gd = reflect_idx(d0 + ld - 2, D);
      int o = (gd * 96 + gh) * 96 + gw;
      float val;
      if (fid == 5) {
        val = pbx[o];
      } else if (fid == 6) {
        val = pby[o];
      } else if (fid == 3 || fid == 4) {
        float bx, by;
        bmask(pbx, pby, bxt, byt, o, bx, by);
        val = (fid == 3) ? bx : by;
      } else if (fid == 0) {
        float x0, y0, x1, y1, x2, y2, x3, y3;
        bmask(pbx, pby, bxt, byt, o, x0, y0);
        bmask(pbx, pby, bxt, byt, o + 1, x1, y1);
        bmask(pbx, pby, bxt, byt, o + 96, x2, y2);
        bmask(pbx, pby, bxt, byt, o + 97, x3, y3);
        val = 0.5f * ((bzp[o] - bzp[o + 96] + bzp[o + 1] - bzp[o + 97]) -
                      (y0 - y1 + y2 - y3));
      } else if (fid == 1) {
        float x0, y0, x1, y1, x2, y2, x3, y3;
        bmask(pbx, pby, bxt, byt, o, x0, y0);
        bmask(pbx, pby, bxt, byt, o + 1, x1, y1);
        bmask(pbx, pby, bxt, byt, o + 9216, x2, y2);
        bmask(pbx, pby, bxt, byt, o + 9217, x3, y3);
        val = 0.5f * ((x0 - x1 + x2 - x3) -
                      (bzp[o] - bzp[o + 9216] + bzp[o + 1] - bzp[o + 9217]));
      } else {  // fid == 2
        float x0, y0, x1, y1, x2, y2, x3, y3;
        bmask(pbx, pby, bxt, byt, o, x0, y0);
        bmask(pbx, pby, bxt, byt, o + 96, x1, y1);
        bmask(pbx, pby, bxt, byt, o + 9216, x2, y2);
        bmask(pbx, pby, bxt, byt, o + 9312, x3, y3);
        val = 0.5f * ((y0 - y2 + y1 - y3) - (x0 - x1 + x2 - x3));
      }
      raw[il] = val;
    }
    __syncthreads();

    for (int i = tid; i < 2048; i += 512) {
      int x = i & 31;
      int h = (i >> 5) & 7;
      int dd = i >> 8;
      int b = dd * 288 + h * 36 + x;
      m1[i] = med5(raw[b], raw[b + 1], raw[b + 2], raw[b + 3], raw[b + 4]);
    }
    __syncthreads();

    for (int i = tid; i < 1024; i += 512) {
      int x = i & 31;
      int y = (i >> 5) & 3;
      int dd = i >> 7;
      int b = dd * 256 + y * 32 + x;
      m2[i] = med5(m1[b], m1[b + 32], m1[b + 64], m1[b + 96], m1[b + 128]);
    }
    __syncthreads();

    const int tx = tid & 31;
    const int ty = (tid >> 5) & 3;
    const int tz = tid >> 7;
    int b = tz * 128 + ty * 32 + tx;
    float med =
        med5(m2[b], m2[b + 128], m2[b + 256], m2[b + 384], m2[b + 512]);
    float center = raw[(tz + 2) * 288 + (ty + 2) * 36 + (tx + 2)];
    float dlt = med - center;
    const int w = w0 + tx;
    const int h = h0 + ty;
    const int d = d0 + tz;
    double c = (w < W && h < H && d < D) ? (double)dlt * (double)dlt : 0.0;
    {
      int lane = tid & 63;
      int wv = tid >> 6;
#pragma unroll
      for (int off = 32; off > 0; off >>= 1) c += __shfl_down(c, off, 64);
      if (lane == 0) sh1[wv] = c;
      __syncthreads();
      if (tid == 0) {
        double bs = 0.0;
#pragma unroll
        for (int i = 0; i < 8; i++) bs += sh1[i];
        M[fid * NMEDBLK + bxi + 3 * (byi + 24 * zb)] = bs;
        __threadfence();
      }
    }
  }

  // ---------- ticket: last block reduces partials and emits ----------
  __syncthreads();
  if (tid == 0) tickS = atomicAdd(done, 1u);
  __syncthreads();
  if (tickS == NTOT - 1) {
    __threadfence();
    for (int q = 0; q < 11; q++) {
      const double* base =
          (q < 4) ? (P + q * NDIVBLK) : (M + (q - 4) * NMEDBLK);
      int cnt = (q < 4) ? NDIVBLK : NMEDBLK;
      double s = 0.0;
      for (int i = tid; i < cnt; i += 512) s += base[i];
      int lane = tid & 63;
      int wv = tid >> 6;
#pragma unroll
      for (int off = 32; off > 0; off >>= 1) s += __shfl_down(s, off, 64);
      if (lane == 0) sh1[wv] = s;
      __syncthreads();
      if (tid == 0) {
        double r = 0.0;
#pragma unroll
        for (int i = 0; i < 8; i++) r += sh1[i];
        fres[q] = r;
      }
      __syncthreads();
    }
    if (tid == 0) {
      const double Nd = 95.0 * 95.0 * 95.0;
      const double Nj = 96.0 * 95.0 * 95.0;
      const double Nv = 96.0 * 96.0 * 96.0;
      double mp = fres[0] / Nd;
      double mt = fres[2] / Nd;
      out[0] = (float)mp;
      out[1] = (float)(fres[1] / Nd - mp * mp);
      out[2] = (float)mt;
      out[3] = (float)(fres[3] / Nd - mt * mt);
      out[4] = (float)((fres[4] + fres[5] + fres[6]) / Nj);
      out[5] = (float)((fres[7] + fres[8] + fres[9] + fres[10]) / Nv);
    }
  }
}

// ---------- launcher ----------

extern "C" void kernel_launch(void* const* d_in, const int* in_sizes, int n_in,
                              void* d_out, int out_size, void* d_ws,
                              size_t ws_size, hipStream_t stream) {
  (void)in_sizes;
  (void)n_in;
  (void)out_size;
  (void)ws_size;
  const float* pred_b = (const float*)d_in[0];
  const float* pred_z = (const float*)d_in[1];
  const float* targets = (const float*)d_in[2];
  float* out = (float*)d_out;

  // ws layout: P (4*NDIVBLK dbl) | M (7*NMEDBLK dbl) | done (u32 padded)
  double* P = (double*)d_ws;
  double* M = P + 4 * NDIVBLK;
  unsigned int* done = (unsigned int*)(M + 7 * NMEDBLK);

  hipMemsetAsync(done, 0, sizeof(unsigned int), stream);

  mega_kernel<<<dim3(NTOT), dim3(512), 0, stream>>>(pred_b, targets, pred_z,
                                                    P, M, done, out);
}